// Round 2
// baseline (77.941 us; speedup 1.0000x reference)
//
#include <hip/hip_runtime.h>
#include <math.h>

// LFQ: D=20 bits, K=2^20, TEMP=0.005, x:[2,128,20] fp32, 256 tokens.
// Factorized softmax over the +-1 hypercube codebook:
//   p_t(k) = prod_j sigma(2 x_tj / T)^(b_kj) * sigma(-2 x_tj / T)^(1-b_kj)
// entropy_t = sum_j H(sigma(400 x_tj));  mean_probs = (1/256) Hi^T Lo with
// 10/10 bit split; mean_entro = -sum_k M_k log(M_k + 1e-10).
//
// R2: fused K3 into K2 (atomic + last-block finalize), double-buffered LDS
// staging in K2 (1 barrier/chunk instead of 2, global loads overlap compute),
// f64 log() -> v_log_f32 (__logf) epilogue.

#define LFQ_D 20
#define NTOK 256
#define NQ (NTOK * LFQ_D)   // 5120

// ws layout (bytes):
//   Hi[t][a] float : 256*1024*4 = 1 MB   @ 0
//   Lo[t][b] float : 1 MB                @ 1 MB
//   entPart[256] double                  @ 2 MB
//   comPart[256] double                  @ 2 MB + 2048
//   meAcc   double                       @ 2 MB + 4096
//   counter int                          @ 2 MB + 4104

__global__ __launch_bounds__(64) void lfq_k1_pertoken(
    const float* __restrict__ x, float* __restrict__ out,
    float* __restrict__ Hi, float* __restrict__ Lo,
    double* __restrict__ entPart, double* __restrict__ comPart,
    double* __restrict__ meAcc, int* __restrict__ counter) {
  const int t = blockIdx.x;
  const int tid = threadIdx.x;
  __shared__ float P1[LFQ_D], P0[LFQ_D];
  __shared__ double hbuf[LFQ_D], cbuf[LFQ_D];
  if (tid < LFQ_D) {
    float xv = x[t * LFQ_D + tid];
    double z = 400.0 * (double)xv;         // 2x/TEMP
    double az = fabs(z);
    double e = exp(-az);                   // underflows to 0 for big |z| -> exact
    double s = e / (1.0 + e);              // sigma(-|z|)
    double p1 = (z >= 0.0) ? (1.0 - s) : s; // P(bit=+1)
    P1[tid] = (float)p1;
    P0[tid] = (float)(1.0 - p1);
    // stable binary entropy in nats: H = log1p(e) + |z| * sigma(-|z|)
    hbuf[tid] = log1p(e) + az * s;
    float qv = (xv > 0.0f) ? 1.0f : -1.0f;
    out[t * LFQ_D + tid] = qv;             // straight-through forward value
    double dx = (double)xv - (double)qv;
    cbuf[tid] = dx * dx;
  }
  if (t == 0 && tid == 32) {               // init accumulators for K2 (ws is poisoned)
    *meAcc = 0.0;
    *counter = 0;
  }
  __syncthreads();
  if (tid == 0) {
    double hs = 0.0, cs = 0.0;
    for (int j = 0; j < LFQ_D; ++j) { hs += hbuf[j]; cs += cbuf[j]; }
    entPart[t] = hs;
    comPart[t] = cs;
  }
  // Hi over high 10 bits (x columns j=0..9): bit_j = (a >> (9-j)) & 1
  for (int a = tid; a < 1024; a += 64) {
    float prod = 1.0f;
#pragma unroll
    for (int j = 0; j < 10; ++j) {
      int bit = (a >> (9 - j)) & 1;
      prod *= bit ? P1[j] : P0[j];
    }
    Hi[t * 1024 + a] = prod;
  }
  // Lo over low 10 bits (x columns j=10..19)
  for (int b = tid; b < 1024; b += 64) {
    float prod = 1.0f;
#pragma unroll
    for (int m = 0; m < 10; ++m) {
      int bit = (b >> (9 - m)) & 1;
      prod *= bit ? P1[10 + m] : P0[10 + m];
    }
    Lo[t * 1024 + b] = prod;
  }
}

// M[a][b] = (1/256) sum_t Hi[t][a] * Lo[t][b];  accumulate -M log(M+1e-10),
// then last-arriving block finalizes all four output scalars.
// Grid 16x16, block 256 (tx=tid&15 -> a, ty=tid>>4 -> b), 4x4 per thread.
// Double-buffered LDS: stage chunk c+1 through registers while computing c.
__global__ __launch_bounds__(256) void lfq_k2_meanentro(
    const float* __restrict__ Hi, const float* __restrict__ Lo,
    const double* __restrict__ entPart, const double* __restrict__ comPart,
    double* __restrict__ meAcc, int* __restrict__ counter,
    float* __restrict__ out) {
  __shared__ float sHi[2][32][64];
  __shared__ float sLo[2][32][64];
  const int tid = threadIdx.x;
  const int tx = tid & 15, ty = tid >> 4;
  const int a0 = blockIdx.x * 64, b0 = blockIdx.y * 64;

  // staging: each thread moves 2 Hi float4s + 2 Lo float4s per 32-t chunk
  const int r0 = tid >> 4;            // rows 0..15
  const int r1 = r0 + 16;             // rows 16..31
  const int c0 = (tid & 15) * 4;      // col 0..60 step 4

  float4 h0 = *(const float4*)&Hi[(0 * 32 + r0) * 1024 + a0 + c0];
  float4 h1 = *(const float4*)&Hi[(0 * 32 + r1) * 1024 + a0 + c0];
  float4 l0 = *(const float4*)&Lo[(0 * 32 + r0) * 1024 + b0 + c0];
  float4 l1 = *(const float4*)&Lo[(0 * 32 + r1) * 1024 + b0 + c0];
  *(float4*)&sHi[0][r0][c0] = h0;
  *(float4*)&sHi[0][r1][c0] = h1;
  *(float4*)&sLo[0][r0][c0] = l0;
  *(float4*)&sLo[0][r1][c0] = l1;
  __syncthreads();

  float acc[4][4];
#pragma unroll
  for (int i = 0; i < 4; ++i)
#pragma unroll
    for (int j = 0; j < 4; ++j) acc[i][j] = 0.0f;

  for (int c = 0; c < 8; ++c) {
    const int cur = c & 1, nxt = cur ^ 1;
    if (c < 7) {  // issue next chunk's global loads before compute
      h0 = *(const float4*)&Hi[((c + 1) * 32 + r0) * 1024 + a0 + c0];
      h1 = *(const float4*)&Hi[((c + 1) * 32 + r1) * 1024 + a0 + c0];
      l0 = *(const float4*)&Lo[((c + 1) * 32 + r0) * 1024 + b0 + c0];
      l1 = *(const float4*)&Lo[((c + 1) * 32 + r1) * 1024 + b0 + c0];
    }
#pragma unroll
    for (int tt = 0; tt < 32; ++tt) {
      float4 ha = *(const float4*)&sHi[cur][tt][tx * 4];
      float4 lb = *(const float4*)&sLo[cur][tt][ty * 4];
      float hav[4] = {ha.x, ha.y, ha.z, ha.w};
      float lbv[4] = {lb.x, lb.y, lb.z, lb.w};
#pragma unroll
      for (int i = 0; i < 4; ++i)
#pragma unroll
        for (int j = 0; j < 4; ++j)
          acc[i][j] = fmaf(hav[i], lbv[j], acc[i][j]);
    }
    if (c < 7) {
      *(float4*)&sHi[nxt][r0][c0] = h0;
      *(float4*)&sHi[nxt][r1][c0] = h1;
      *(float4*)&sLo[nxt][r0][c0] = l0;
      *(float4*)&sLo[nxt][r1][c0] = l1;
    }
    __syncthreads();
  }

  // epilogue: -m*log(m+1e-10) with HW v_log_f32 (abs err per term ~4e-6 * m)
  float tsum = 0.0f;
#pragma unroll
  for (int i = 0; i < 4; ++i)
#pragma unroll
    for (int j = 0; j < 4; ++j) {
      float m = acc[i][j] * (1.0f / 256.0f);
      tsum -= m * __logf(m + 1e-10f);
    }
  __shared__ double red[256];
  red[tid] = (double)tsum;
  __syncthreads();
  for (int s = 128; s > 0; s >>= 1) {
    if (tid < s) red[tid] += red[tid + s];
    __syncthreads();
  }

  __shared__ int lastFlag;
  if (tid == 0) {
    atomicAdd(meAcc, red[0]);
    __threadfence();
    int old = atomicAdd(counter, 1);
    lastFlag = (old == 255) ? 1 : 0;
  }
  __syncthreads();
  if (lastFlag) {  // block-uniform; 256 threads finalize
    __shared__ double r1[256], r2[256];
    r1[tid] = entPart[tid];
    r2[tid] = comPart[tid];
    __syncthreads();
    for (int s = 128; s > 0; s >>= 1) {
      if (tid < s) { r1[tid] += r1[tid + s]; r2[tid] += r2[tid + s]; }
      __syncthreads();
    }
    if (tid == 0) {
      double me = atomicAdd(meAcc, 0.0);   // atomic read, all 256 adds visible
      double entro_mean_s = r1[0] / 256.0;
      double commit = r2[0] / (double)NQ;
      out[NQ + 0] = (float)entro_mean_s;
      out[NQ + 1] = (float)me;
      out[NQ + 2] = (float)(entro_mean_s - me);  // ALPHA=1
      out[NQ + 3] = (float)commit;
    }
  }
}

extern "C" void kernel_launch(void* const* d_in, const int* in_sizes, int n_in,
                              void* d_out, int out_size, void* d_ws, size_t ws_size,
                              hipStream_t stream) {
  const float* x = (const float*)d_in[0];
  float* out = (float*)d_out;
  char* ws = (char*)d_ws;
  float* Hi = (float*)(ws);
  float* Lo = (float*)(ws + (1u << 20));
  double* entPart = (double*)(ws + (2u << 20));
  double* comPart = (double*)(ws + (2u << 20) + 2048);
  double* meAcc   = (double*)(ws + (2u << 20) + 4096);
  int*    counter = (int*)   (ws + (2u << 20) + 4104);

  lfq_k1_pertoken<<<NTOK, 64, 0, stream>>>(x, out, Hi, Lo, entPart, comPart,
                                           meAcc, counter);
  lfq_k2_meanentro<<<dim3(16, 16), 256, 0, stream>>>(Hi, Lo, entPart, comPart,
                                                     meAcc, counter, out);
}